// Round 1
// baseline (171.604 us; speedup 1.0000x reference)
//
#include <hip/hip_runtime.h>

// Conv2d: x[4, 4096, 4096] fp32, kernel[4,4,3,3] fp32, pad=1, stride=1
// out[4, 4096, 4096] fp32.
//
// One thread computes 4 consecutive output x positions for ALL 4 output
// channels (16 accumulators). Per (cin, ky): one aligned float4 load + two
// scalar halo loads (L1 hits). 576 FMAs/thread. Memory-bound: ideal HBM
// traffic 512 MB.

#define IW 4096
#define IH 4096
#define NC 4
constexpr int HWsz = IH * IW;

__global__ __launch_bounds__(256) void conv3x3_kernel(
    const float* __restrict__ xin,   // [4][4096][4096]
    const float* __restrict__ wt,    // [4][4][3][3]
    float* __restrict__ out)         // [4][4096][4096]
{
    // 16384 blocks total; XCD-aware bijective swizzle (nwg % 8 == 0):
    // each XCD gets 2048 consecutive block ids = 512 consecutive rows,
    // so the 3-row vertical reuse window stays in that XCD's L2.
    const int nwg = 16384;
    const int cpx = nwg >> 3;                 // 2048 blocks per XCD chunk
    int bid = blockIdx.x;
    int swz = (bid & 7) * cpx + (bid >> 3);

    const int tid = threadIdx.x;
    // Each block: 256 threads x 4 px = 1024 px = one quarter of a row.
    const int y  = swz >> 2;                  // output row
    const int bx = swz & 3;                   // quarter-row index
    const int x0 = (bx * 256 + tid) * 4;      // first output x (16B aligned)

    float acc[4][4];                          // [cout][x]
    #pragma unroll
    for (int co = 0; co < 4; ++co)
        #pragma unroll
        for (int xo = 0; xo < 4; ++xo) acc[co][xo] = 0.f;

    #pragma unroll
    for (int ci = 0; ci < 4; ++ci) {
        const float* plane = xin + ci * HWsz;
        #pragma unroll
        for (int r = 0; r < 3; ++r) {
            const int yy = y + r - 1;
            float vals[6];
            if (yy >= 0 && yy < IH) {         // wave-uniform branch
                const float* rowp = plane + (long)yy * IW;
                const float4 v = *reinterpret_cast<const float4*>(rowp + x0);
                vals[1] = v.x; vals[2] = v.y; vals[3] = v.z; vals[4] = v.w;
                vals[0] = (x0 > 0)       ? rowp[x0 - 1] : 0.f;  // halo: L1 hit
                vals[5] = (x0 + 4 < IW)  ? rowp[x0 + 4] : 0.f;  // halo: L1 hit
            } else {
                #pragma unroll
                for (int t = 0; t < 6; ++t) vals[t] = 0.f;
            }
            #pragma unroll
            for (int co = 0; co < 4; ++co) {
                #pragma unroll
                for (int kx = 0; kx < 3; ++kx) {
                    // uniform address, constant offset -> scalar-cache load
                    const float w = wt[((co * 4 + ci) * 3 + r) * 3 + kx];
                    #pragma unroll
                    for (int xo = 0; xo < 4; ++xo)
                        acc[co][xo] = fmaf(w, vals[xo + kx], acc[co][xo]);
                }
            }
        }
    }

    #pragma unroll
    for (int co = 0; co < 4; ++co) {
        float4 o;
        o.x = acc[co][0]; o.y = acc[co][1]; o.z = acc[co][2]; o.w = acc[co][3];
        *reinterpret_cast<float4*>(out + co * HWsz + (long)y * IW + x0) = o;
    }
}

extern "C" void kernel_launch(void* const* d_in, const int* in_sizes, int n_in,
                              void* d_out, int out_size, void* d_ws, size_t ws_size,
                              hipStream_t stream) {
    const float* xin = (const float*)d_in[0];
    const float* wt  = (const float*)d_in[1];
    float* out       = (float*)d_out;

    dim3 grid(16384), block(256);
    hipLaunchKernelGGL(conv3x3_kernel, grid, block, 0, stream, xin, wt, out);
}